// Round 20
// baseline (378.552 us; speedup 1.0000x reference)
//
#include <hip/hip_runtime.h>
#include <float.h>

// Problem constants
#define NROWS 65536      // B*H*W*D
#define CDIM  256
#define KS    1024
#define KY    512
#define KTOT  1536
#define SPB   4096       // H*W*D per batch

// ---- workspace byte offsets ----
#define WB_CNT_S       0         // 1024 int
#define WB_CNT_Y       4096      // 512 int
#define WB_RESCUE_CNT  6144      // 2 int
#define WB_DISACC      6152      // 1 float
#define WB_DW_S        6400      // 1024*256 f32
#define WB_DW_Y        1054976   // 512*256 f32
#define WB_ZERO_BYTES  1579264   // memset [0, here)
#define WB_EIMG        1579264   // 96 chunks * 8192 B (fp16 image, 16 codes/chunk)
#define WB_EN2         2365696   // 1536 f32
#define WB_IDXS_I      2371840   // 65536 int
#define WB_IDXY_I      2633984   // 65536 int
#define WB_RLIST_Y     3158272   // 65536 int
#define WB_CUR_S       3426560   // 1024 int
#define WB_CUR_Y       3430656   // 512 int
#define WB_SCALE_S     3432704   // 1024 f32
#define WB_SCALE_Y     3436800   // 512 f32
#define WB_PERM_S      3438848   // 65536 int
#define WB_PERM_Y      3700992   // 65536 int
#define WB_KSORT_S     3963136   // 65536 int
#define WB_KSORT_Y     4225280   // 65536 int
#define WB_PS0         4487424   // 65536 uint2
#define WB_PS1         5011712   // 65536 uint2

// ---- output float offsets ----
#define OFF_OUT_ZQ   0
#define OFF_OUT_DIS  16777216
#define OFF_OUT_SIDX 16777217
#define OFF_OUT_YIDX 16842753

typedef __attribute__((ext_vector_type(8)))  _Float16 f16x8;
typedef __attribute__((ext_vector_type(4)))  float    f32x4;

__device__ __forceinline__ unsigned int umn(unsigned int a, unsigned int b) { return a < b ? a : b; }
__device__ __forceinline__ unsigned int umx(unsigned int a, unsigned int b) { return a > b ? a : b; }

// ---------------------------------------------------------------------------
// Codebook prep: fp16 fragment image + |e|^2. 384 blocks x 4 waves = 1536 codes.
__global__ void prep_e(const float* __restrict__ Es, const float* __restrict__ Ey,
                       unsigned short* __restrict__ eimg, float* __restrict__ en2) {
    int wave = threadIdx.x >> 6, lane = threadIdx.x & 63;
    int k = blockIdx.x * 4 + wave;       // 0..1535
    const float* E = (k < KS) ? (Es + (size_t)k * CDIM) : (Ey + (size_t)(k - KS) * CDIM);
    float4 v = *(const float4*)(E + lane * 4);
    float nrm = v.x * v.x + v.y * v.y + v.z * v.z + v.w * v.w;
#pragma unroll
    for (int off = 32; off > 0; off >>= 1) nrm += __shfl_down(nrm, off);
    if (lane == 0) en2[k] = nrm;

    unsigned short q0 = __builtin_bit_cast(unsigned short, (_Float16)v.x);
    unsigned short q1 = __builtin_bit_cast(unsigned short, (_Float16)v.y);
    unsigned short q2 = __builtin_bit_cast(unsigned short, (_Float16)v.z);
    unsigned short q3 = __builtin_bit_cast(unsigned short, (_Float16)v.w);
    uint2 hp = make_uint2((unsigned)q0 | ((unsigned)q1 << 16),
                          (unsigned)q2 | ((unsigned)q3 << 16));
    int c0 = lane * 4;
    int kc = c0 >> 5, g = (c0 >> 3) & 3, j0 = c0 & 7;
    size_t byteoff = (size_t)(k >> 4) * 8192 + (size_t)kc * 1024
                   + (size_t)(g * 16 + (k & 15)) * 16 + (size_t)j0 * 2;
    *(uint2*)((char*)eimg + byteoff) = hp;
}

// ---------------------------------------------------------------------------
__device__ __forceinline__ void stage1(const unsigned short* __restrict__ eimg,
                                       int chunk, char* lds, int wave, int lane) {
    const char* gs = (const char*)eimg + (size_t)chunk * 8192 + wave * 2048 + lane * 16;
    char* ls = lds + wave * 2048;
    __builtin_amdgcn_global_load_lds(
        (const __attribute__((address_space(1))) void*)gs,
        (__attribute__((address_space(3))) void*)ls, 16, 0, 0);
    __builtin_amdgcn_global_load_lds(
        (const __attribute__((address_space(1))) void*)(gs + 1024),
        (__attribute__((address_space(3))) void*)(ls + 1024), 16, 0, 0);
}

#define WAITV(n)                                                               \
    asm volatile("s_waitcnt vmcnt(" #n ")");                                   \
    __builtin_amdgcn_sched_barrier(0);

#define PSFLUSH(dst)                                                           \
    {                                                                          \
        _Pragma("unroll")                                                      \
        for (int rg = 0; rg < 2; ++rg)                                         \
        _Pragma("unroll")                                                      \
        for (int q = 0; q < 4; ++q) {                                          \
            unsigned int v1 = m1a[rg][q], v2 = m2a[rg][q];                     \
            _Pragma("unroll")                                                  \
            for (int m = 8; m >= 1; m >>= 1) {                                 \
                unsigned int o1 = (unsigned int)__shfl_xor((int)v1, m);        \
                unsigned int o2 = (unsigned int)__shfl_xor((int)v2, m);        \
                v2 = umn(umn(v2, o2), umx(v1, o1));                            \
                v1 = umn(v1, o1);                                              \
            }                                                                  \
            if ((lane & 15) == 0) {                                            \
                int n = n0 + rg * 16 + (lane >> 4) * 4 + q;                    \
                dst[n] = make_uint2(v1, v2);                                   \
            }                                                                  \
            m1a[rg][q] = 0xFFFFFFFFu; m2a[rg][q] = 0xFFFFFFFFu;                \
        }                                                                      \
    }

#define FLUSHY()                                                               \
    {                                                                          \
        _Pragma("unroll")                                                      \
        for (int rg = 0; rg < 2; ++rg)                                         \
        _Pragma("unroll")                                                      \
        for (int q = 0; q < 4; ++q) {                                          \
            unsigned int v1 = m1a[rg][q], v2 = m2a[rg][q];                     \
            _Pragma("unroll")                                                  \
            for (int m = 8; m >= 1; m >>= 1) {                                 \
                unsigned int o1 = (unsigned int)__shfl_xor((int)v1, m);        \
                unsigned int o2 = (unsigned int)__shfl_xor((int)v2, m);        \
                v2 = umn(umn(v2, o2), umx(v1, o1));                            \
                v1 = umn(v1, o1);                                              \
            }                                                                  \
            if ((lane & 15) == 0) {                                            \
                int kw = (int)(v1 & 0x7FFu) - KS;                              \
                int n = n0 + rg * 16 + (lane >> 4) * 4 + q;                    \
                yidx_f[n] = (float)kw;                                         \
                yidx_i[n] = kw;                                                \
                atomicAdd(&cnt_y[kw], 1);                                      \
                if ((v1 >> 11) + 4 > (v2 >> 11)) {                             \
                    int k2w = (int)(v2 & 0x7FFu) - KS;                         \
                    int pp = atomicAdd(&rescue_cnt[1], 1);                     \
                    if (pp < 65536) rlist_y[pp] = n | (k2w << 16);             \
                }                                                              \
            }                                                                  \
        }                                                                      \
    }

// ---------------------------------------------------------------------------
// Fused phase-1: blocks [0,1024) = MFMA assign (reads z directly);
// blocks [1024,3072) = z -> zf transpose (fills assign's idle slots).
// R20: 3-deep chunk buffers (24KB) + en2l (6KB) = 30KB LDS; transpose uses a
// 16-row two-pass tile (16.4KB) -> 5 blocks/CU (launch_bounds(256,5)), 20
// waves/CU vs R19's 16. 3-deep is race-free: stage(i+2) is issued after
// barrier(i), and barrier(i+1) separates any wave's stage(i+3) from the
// slowest wave's compute(i) reading buf[i%3].
__launch_bounds__(256, 5)
__global__ void main1_kernel(const float* __restrict__ z, const unsigned short* __restrict__ eimg,
                             const float* __restrict__ en2g, float* __restrict__ zf,
                             uint2* __restrict__ ps0, uint2* __restrict__ ps1,
                             float* __restrict__ yidx_f, int* __restrict__ yidx_i,
                             int* __restrict__ cnt_y, int* __restrict__ rescue_cnt,
                             int* __restrict__ rlist_y) {
    __shared__ char lds_raw[30720];        // assign: 3x8KB bufs + 6KB en2l; transpose: 16x257 f32

    if (blockIdx.x < 1024) {
        char (*sh)[8192] = (char(*)[8192])lds_raw;
        float* en2l = (float*)(lds_raw + 24576);
        const int tid = threadIdx.x, wave = tid >> 6, lane = tid & 63;
        const int half = blockIdx.x & 1;
        const int n0 = (blockIdx.x >> 1) * 128 + wave * 32;
        const int cb = half * 48;

        for (int i = tid; i < KTOT; i += 256) en2l[i] = en2g[i];

        const int b = n0 >> 12;
        const int sb = (n0 & 4095) + (lane & 15);
        const float* zb = z + (size_t)b * CDIM * SPB;
        const int g8 = (lane >> 4) * 8;
        f16x8 A[2][8];
#pragma unroll
        for (int rg = 0; rg < 2; ++rg) {
#pragma unroll
            for (int kc = 0; kc < 8; ++kc) {
                f16x8 a;
#pragma unroll
                for (int j = 0; j < 8; ++j)
                    a[j] = (_Float16)zb[(size_t)(g8 + kc * 32 + j) * SPB + sb + rg * 16];
                A[rg][kc] = a;
            }
        }

        unsigned int m1a[2][4], m2a[2][4];
#pragma unroll
        for (int rg = 0; rg < 2; ++rg)
#pragma unroll
            for (int q = 0; q < 4; ++q) { m1a[rg][q] = 0xFFFFFFFFu; m2a[rg][q] = 0xFFFFFFFFu; }

        stage1(eimg, cb + 0, &sh[0][0], wave, lane);
        stage1(eimg, cb + 1, &sh[1][0], wave, lane);
        __syncthreads();

        int bc = 0, bs = 2;                // compute buf, stage buf (i+2)%3
#pragma unroll 1
        for (int i = 0; i < 48; ++i) {
            if (i < 47) { WAITV(2); }      // chunk i landed; chunk i+1 in flight
            else        { WAITV(0); }
            __builtin_amdgcn_s_barrier();
            asm volatile("" ::: "memory");
            if (i + 2 < 48) stage1(eimg, cb + i + 2, &sh[bs][0], wave, lane);

            const int chunk = cb + i;
            const char* bb = &sh[bc][0] + lane * 16;
            f32x4 acc0 = {}, acc1 = {};
#pragma unroll
            for (int kc = 0; kc < 8; ++kc) {
                f16x8 B = *(const f16x8*)(bb + kc * 1024);
                acc0 = __builtin_amdgcn_mfma_f32_16x16x32_f16(A[0][kc], B, acc0, 0, 0, 0);
                acc1 = __builtin_amdgcn_mfma_f32_16x16x32_f16(A[1][kc], B, acc1, 0, 0, 0);
            }
            const int kcode = chunk * 16 + (lane & 15);
            const float en0 = en2l[kcode] + 512.0f;
            const unsigned int tag = (unsigned int)kcode;
#pragma unroll
            for (int q = 0; q < 4; ++q) {
                float d0 = fmaf(-2.f, acc0[q], en0);
                unsigned int du0 = (__float_as_uint(d0) & 0xFFFFF800u) | tag;
                m2a[0][q] = umn(m2a[0][q], umx(m1a[0][q], du0));
                m1a[0][q] = umn(m1a[0][q], du0);
                float d1 = fmaf(-2.f, acc1[q], en0);
                unsigned int du1 = (__float_as_uint(d1) & 0xFFFFF800u) | tag;
                m2a[1][q] = umn(m2a[1][q], umx(m1a[1][q], du1));
                m1a[1][q] = umn(m1a[1][q], du1);
            }

            if (half == 1 && i == 15) PSFLUSH(ps1);

            bc = (bc == 2) ? 0 : bc + 1;
            bs = (bs == 2) ? 0 : bs + 1;
        }

        if (half == 0) { PSFLUSH(ps0); }
        else           { FLUSHY(); }
    } else {
        // z -> zf transpose, 16-row two-pass tile (16.4KB LDS)
        float (*Zs)[257] = (float(*)[257])lds_raw;
        int blk = blockIdx.x - 1024;
        int n0 = blk * 32, b = n0 >> 12, s0 = n0 & 4095;
        int t = threadIdx.x;
        const float* zb = z + (size_t)b * CDIM * SPB + s0;
#pragma unroll 1
        for (int p = 0; p < 2; ++p) {
            __syncthreads();
#pragma unroll
            for (int i = 0; i < 16; ++i) {
                int l = i * 256 + t;
                int c = l >> 4, s = l & 15;
                Zs[s][c] = zb[(size_t)c * SPB + p * 16 + s];
            }
            __syncthreads();
#pragma unroll
            for (int j = 0; j < 4; ++j) {
                int gid = j * 256 + t;
                int nl = gid >> 6, fg = gid & 63;
                float4 v = *(const float4*)(&Zs[nl][fg * 4]);
                *(float4*)(&zf[(size_t)(n0 + p * 16 + nl) * 256 + fg * 4]) = v;
            }
        }
    }
}

// ---------------------------------------------------------------------------
// Fused merge + rescue: blocks [0,256) merge book-S partials for their 256
// rows, queue near-ties in LDS, then re-rank them exactly (block-local).
// Blocks [256,512) drain the Y rescue list from main1.
__global__ void merge_rescue_kernel(const float* __restrict__ zf,
                                    const float* __restrict__ Es, const float* __restrict__ Ey,
                                    const float* __restrict__ en2,
                                    const uint2* __restrict__ ps0, const uint2* __restrict__ ps1,
                                    float* __restrict__ sidx_f, float* __restrict__ yidx_f,
                                    int* __restrict__ sidx_i, int* __restrict__ yidx_i,
                                    int* __restrict__ cnt_s, int* __restrict__ cnt_y,
                                    const int* __restrict__ rcnt_y, const int* __restrict__ rlist_y) {
    const int t = threadIdx.x, lane = t & 63, wv = t >> 6;
    if (blockIdx.x < 256) {
        __shared__ int qn[256], qk2[256];
        __shared__ int qc;
        if (t == 0) qc = 0;
        __syncthreads();
        int n = blockIdx.x * 256 + t;
        uint2 pa = ps0[n], pb = ps1[n];
        unsigned int v1 = umn(pa.x, pb.x);
        unsigned int v2 = umn(umn(pa.y, pb.y), umx(pa.x, pb.x));
        int kw = (int)(v1 & 0x7FFu);
        sidx_f[n] = (float)kw;
        sidx_i[n] = kw;
        atomicAdd(&cnt_s[kw], 1);
        if ((v1 >> 11) + 4 > (v2 >> 11)) {
            int p = atomicAdd(&qc, 1);
            qn[p] = n;
            qk2[p] = (int)(v2 & 0x7FFu);
        }
        __syncthreads();
        int ce = qc;
        for (int e = wv; e < ce; e += 4) {
            int nn = qn[e], k2 = qk2[e];
            int k1 = sidx_i[nn];
            float4 zv = *(const float4*)(zf + (size_t)nn * 256 + lane * 4);
            float4 ea = *(const float4*)(Es + (size_t)k1 * 256 + lane * 4);
            float4 ec = *(const float4*)(Es + (size_t)k2 * 256 + lane * 4);
            float d1 = zv.x * ea.x + zv.y * ea.y + zv.z * ea.z + zv.w * ea.w;
            float d2 = zv.x * ec.x + zv.y * ec.y + zv.z * ec.z + zv.w * ec.w;
#pragma unroll
            for (int off = 32; off > 0; off >>= 1) {
                d1 += __shfl_down(d1, off);
                d2 += __shfl_down(d2, off);
            }
            if (lane == 0) {
                float dist1 = en2[k1] - 2.f * d1;
                float dist2 = en2[k2] - 2.f * d2;
                int nk = (dist2 < dist1 || (dist2 == dist1 && k2 < k1)) ? k2 : k1;
                if (nk != k1) {
                    atomicSub(&cnt_s[k1], 1);
                    atomicAdd(&cnt_s[nk], 1);
                    sidx_i[nn] = nk;
                    sidx_f[nn] = (float)nk;
                }
            }
        }
    } else {
        int cy = *rcnt_y; if (cy > 65536) cy = 65536;
        const int nw = 256 * 4;
        for (int e = (blockIdx.x - 256) * 4 + wv; e < cy; e += nw) {
            unsigned int ent = (unsigned int)rlist_y[e];
            int nn = (int)(ent & 0xFFFFu);
            int k2 = (int)(ent >> 16);
            int k1 = yidx_i[nn];
            float4 zv = *(const float4*)(zf + (size_t)nn * 256 + lane * 4);
            float4 ea = *(const float4*)(Ey + (size_t)k1 * 256 + lane * 4);
            float4 ec = *(const float4*)(Ey + (size_t)k2 * 256 + lane * 4);
            float d1 = zv.x * ea.x + zv.y * ea.y + zv.z * ea.z + zv.w * ea.w;
            float d2 = zv.x * ec.x + zv.y * ec.y + zv.z * ec.z + zv.w * ec.w;
#pragma unroll
            for (int off = 32; off > 0; off >>= 1) {
                d1 += __shfl_down(d1, off);
                d2 += __shfl_down(d2, off);
            }
            if (lane == 0) {
                float dist1 = en2[KS + k1] - 2.f * d1;
                float dist2 = en2[KS + k2] - 2.f * d2;
                int nk = (dist2 < dist1 || (dist2 == dist1 && k2 < k1)) ? k2 : k1;
                if (nk != k1) {
                    atomicSub(&cnt_y[k1], 1);
                    atomicAdd(&cnt_y[nk], 1);
                    yidx_i[nn] = nk;
                    yidx_f[nn] = (float)nk;
                }
            }
        }
    }
}

// ---------------------------------------------------------------------------
// Per-codebook: prefix-sum of counts (sort bases) + EMA balance scale.
__global__ void scanbal_kernel(const float* __restrict__ cs_in, const float* __restrict__ cy_in,
                               const int* __restrict__ cnt_s, const int* __restrict__ cnt_y,
                               int* __restrict__ cur_s, int* __restrict__ cur_y,
                               float* __restrict__ scale_s, float* __restrict__ scale_y) {
    __shared__ int   sc[1024];
    __shared__ float sf[1024];
    int K = blockIdx.x ? KY : KS;
    const float* csi = blockIdx.x ? cy_in : cs_in;
    const int*   cnt = blockIdx.x ? cnt_y : cnt_s;
    int* cur  = blockIdx.x ? cur_y  : cur_s;
    float* scale = blockIdx.x ? scale_y : scale_s;
    int t = threadIdx.x;
    int c = (t < K) ? cnt[t] : 0;
    float ncs = (t < K) ? (csi[t] * 0.99f + 0.01f * (float)c) : 0.f;
    sc[t] = c;
    __syncthreads();
    for (int off = 1; off < 1024; off <<= 1) {
        int v = sc[t] + ((t >= off) ? sc[t - off] : 0);
        __syncthreads();
        sc[t] = v;
        __syncthreads();
    }
    int incl = sc[t];
    sf[t] = ncs;
    __syncthreads();
    for (int s2 = 512; s2 > 0; s2 >>= 1) {
        if (t < s2) sf[t] += sf[t + s2];
        __syncthreads();
    }
    float nsum = sf[0];
    if (t < K) {
        cur[t]  = incl - c;
        float bal = (ncs + 1e-5f) / (nsum + (float)K * 1e-5f) * nsum;
        scale[t] = 1.0f / bal;
    }
}

__global__ void scatter_kernel(const int* __restrict__ si, const int* __restrict__ yi,
                               int* __restrict__ cur_s, int* __restrict__ cur_y,
                               int* __restrict__ perm_s, int* __restrict__ perm_y,
                               int* __restrict__ ksort_s, int* __restrict__ ksort_y) {
    int i = blockIdx.x * 256 + threadIdx.x;
    if (i < NROWS) {
        int k = si[i]; int p = atomicAdd(&cur_s[k], 1);
        perm_s[p] = i; ksort_s[p] = k;
    } else {
        int n = i - NROWS; int k = yi[n]; int p = atomicAdd(&cur_y[k], 1);
        perm_y[p] = n; ksort_y[p] = k;
    }
}

// ---------------------------------------------------------------------------
// Chunked segmented sum over sorted rows: block = 64 sorted positions.
__global__ void dw_kernel(const float* __restrict__ zf,
                          const int* __restrict__ perm_s, const int* __restrict__ ksort_s,
                          const int* __restrict__ perm_y, const int* __restrict__ ksort_y,
                          float* __restrict__ dw_s, float* __restrict__ dw_y) {
    __shared__ int keys[65];
    __shared__ int rows[64];
    const int t = threadIdx.x;
    int blk = blockIdx.x;
    const int* perm; const int* ks; float* dw; int p0;
    if (blk < NROWS / 64) { perm = perm_s; ks = ksort_s; dw = dw_s; p0 = blk * 64; }
    else                  { perm = perm_y; ks = ksort_y; dw = dw_y; p0 = (blk - NROWS / 64) * 64; }
    if (t < 64) { keys[t] = ks[p0 + t]; rows[t] = perm[p0 + t]; }
    if (t == 64) keys[64] = -1;
    __syncthreads();
    float acc = 0.f;
#pragma unroll 8
    for (int j = 0; j < 64; ++j) {
        acc += zf[(size_t)rows[j] * 256 + t];
        if (keys[j + 1] != keys[j]) {
            atomicAdd(&dw[(size_t)keys[j] * 256 + t], acc);
            acc = 0.f;
        }
    }
}

// ---------------------------------------------------------------------------
// Gather with on-the-fly emb computation (plain atomicAdd for dis; no
// device-scope fences). zq written with float4 stores.
__global__ void gather_kernel(const float* __restrict__ avg_s, const float* __restrict__ avg_y,
                              const float* __restrict__ dw_s, const float* __restrict__ dw_y,
                              const float* __restrict__ scale_s, const float* __restrict__ scale_y,
                              const int* __restrict__ sidx, const int* __restrict__ yidx,
                              float* __restrict__ zq, float* __restrict__ disacc) {
    __shared__ float qb[256 * 17];
    __shared__ int   si[16], yi[16];
    __shared__ float scs[16], scy[16];
    __shared__ float red[256];
    const int g  = blockIdx.x;        // b*256 + hw
    const int b  = g >> 8;
    const int hw = g & 255;
    const int t  = threadIdx.x;       // channel
    if (t < 16) {
        int n = b * SPB + hw * 16 + t;
        int k = sidx[n];
        si[t] = k;
        scs[t] = scale_s[k];
    } else if (t < 32) {
        int n = b * SPB + hw * 16 + (t - 16);
        int k = yidx[n];
        yi[t - 16] = k;
        scy[t - 16] = scale_y[k];
    }
    __syncthreads();
    float ns = 0.f, ny = 0.f, dot = 0.f;
#pragma unroll
    for (int d = 0; d < 16; ++d) {
        size_t so = (size_t)si[d] * CDIM + t;
        size_t yo = (size_t)yi[d] * CDIM + t;
        float s = fmaf(0.01f, dw_s[so], avg_s[so] * 0.99f) * scs[d];
        float y = fmaf(0.01f, dw_y[yo], avg_y[yo] * 0.99f) * scy[d];
        ns  = fmaf(s, s, ns);
        ny  = fmaf(y, y, ny);
        dot = fmaf(s, y, dot);
        qb[t * 17 + d] = 0.5f * (s + y);
    }
    float den = fmaxf(sqrtf(ns), 1e-12f) * fmaxf(sqrtf(ny), 1e-12f);
    float val = dot / den;
    red[t] = val * val;
    __syncthreads();
    for (int s = 128; s > 0; s >>= 1) {
        if (t < s) red[t] += red[t + s];
        __syncthreads();
    }
    if (t == 0) atomicAdd(disacc, red[0]);
    float* zg = zq + (size_t)b * CDIM * SPB + hw * 16;
    // float4 stores: thread covers 4 float4s; 4 consecutive lanes fill one c-row
#pragma unroll
    for (int j = 0; j < 4; ++j) {
        int f = j * 256 + t;          // float4 index
        int c = f >> 2, q = f & 3;
        float4 v;
        v.x = qb[c * 17 + q * 4 + 0];
        v.y = qb[c * 17 + q * 4 + 1];
        v.z = qb[c * 17 + q * 4 + 2];
        v.w = qb[c * 17 + q * 4 + 3];
        *(float4*)(&zg[(size_t)c * SPB + q * 4]) = v;
    }
}

__global__ void fin_kernel(const float* __restrict__ disacc, float* __restrict__ out_dis) {
    *out_dis = *disacc * (1.0f / 1048576.0f);
}

// ---------------------------------------------------------------------------
extern "C" void kernel_launch(void* const* d_in, const int* in_sizes, int n_in,
                              void* d_out, int out_size, void* d_ws, size_t ws_size,
                              hipStream_t stream) {
    const float* z     = (const float*)d_in[0];
    const float* Es    = (const float*)d_in[1];
    const float* Ey    = (const float*)d_in[2];
    const float* s_cs  = (const float*)d_in[3];
    const float* y_cs  = (const float*)d_in[4];
    const float* s_avg = (const float*)d_in[5];
    const float* y_avg = (const float*)d_in[6];
    float* out = (float*)d_out;
    char*  w   = (char*)d_ws;

    unsigned short* eimg = (unsigned short*)(w + WB_EIMG);
    float* en2    = (float*)(w + WB_EN2);
    int* idxs_i   = (int*)(w + WB_IDXS_I);
    int* idxy_i   = (int*)(w + WB_IDXY_I);
    int* cnt_s    = (int*)(w + WB_CNT_S);
    int* cnt_y    = (int*)(w + WB_CNT_Y);
    int* r_cnt    = (int*)(w + WB_RESCUE_CNT);
    int* rlist_y  = (int*)(w + WB_RLIST_Y);
    int* cur_s    = (int*)(w + WB_CUR_S);
    int* cur_y    = (int*)(w + WB_CUR_Y);
    float* scale_s = (float*)(w + WB_SCALE_S);
    float* scale_y = (float*)(w + WB_SCALE_Y);
    int* perm_s   = (int*)(w + WB_PERM_S);
    int* perm_y   = (int*)(w + WB_PERM_Y);
    int* ksort_s  = (int*)(w + WB_KSORT_S);
    int* ksort_y  = (int*)(w + WB_KSORT_Y);
    float* dw_s   = (float*)(w + WB_DW_S);
    float* dw_y   = (float*)(w + WB_DW_Y);
    uint2* ps0    = (uint2*)(w + WB_PS0);
    uint2* ps1    = (uint2*)(w + WB_PS1);

    float* zf     = out + OFF_OUT_ZQ;        // zq region reused as fp32 z^T scratch
    float* sidx_f = out + OFF_OUT_SIDX;
    float* yidx_f = out + OFF_OUT_YIDX;

    hipMemsetAsync(w, 0, WB_ZERO_BYTES, stream);

    prep_e<<<384, 256, 0, stream>>>(Es, Ey, eimg, en2);

    main1_kernel<<<1024 + 2048, 256, 0, stream>>>(
        z, eimg, en2, zf, ps0, ps1, yidx_f, idxy_i, cnt_y, r_cnt, rlist_y);

    merge_rescue_kernel<<<512, 256, 0, stream>>>(zf, Es, Ey, en2, ps0, ps1,
                                                 sidx_f, yidx_f, idxs_i, idxy_i,
                                                 cnt_s, cnt_y, r_cnt + 1, rlist_y);

    scanbal_kernel<<<2, 1024, 0, stream>>>(s_cs, y_cs, cnt_s, cnt_y,
                                           cur_s, cur_y, scale_s, scale_y);
    scatter_kernel<<<2 * NROWS / 256, 256, 0, stream>>>(idxs_i, idxy_i, cur_s, cur_y,
                                                        perm_s, perm_y, ksort_s, ksort_y);
    dw_kernel<<<2 * NROWS / 64, 256, 0, stream>>>(zf, perm_s, ksort_s, perm_y, ksort_y, dw_s, dw_y);
    gather_kernel<<<4096, 256, 0, stream>>>(s_avg, y_avg, dw_s, dw_y, scale_s, scale_y,
                                            idxs_i, idxy_i,
                                            out + OFF_OUT_ZQ, (float*)(w + WB_DISACC));
    fin_kernel<<<1, 1, 0, stream>>>((float*)(w + WB_DISACC), out + OFF_OUT_DIS);
}

// Round 21
// 303.060 us; speedup vs baseline: 1.2491x; 1.2491x over previous
//
#include <hip/hip_runtime.h>
#include <float.h>

// Problem constants
#define NROWS 65536      // B*H*W*D
#define CDIM  256
#define KS    1024
#define KY    512
#define KTOT  1536
#define SPB   4096       // H*W*D per batch

// ---- workspace byte offsets ----
#define WB_CNT_S       0         // 1024 int
#define WB_CNT_Y       4096      // 512 int
#define WB_RESCUE_CNT  6144      // 2 int
#define WB_DISACC      6152      // 1 float
#define WB_DW_S        6400      // 1024*256 f32
#define WB_DW_Y        1054976   // 512*256 f32
#define WB_ZERO_BYTES  1579264   // memset [0, here)
#define WB_EIMG        1579264   // 96 chunks * 8192 B (fp16 image, 16 codes/chunk)
#define WB_EN2         2365696   // 1536 f32
#define WB_IDXS_I      2371840   // 65536 int
#define WB_IDXY_I      2633984   // 65536 int
#define WB_RLIST_Y     3158272   // 65536 int
#define WB_CUR_S       3426560   // 1024 int
#define WB_CUR_Y       3430656   // 512 int
#define WB_SCALE_S     3432704   // 1024 f32
#define WB_SCALE_Y     3436800   // 512 f32
#define WB_PERM_S      3438848   // 65536 int
#define WB_PERM_Y      3700992   // 65536 int
#define WB_KSORT_S     3963136   // 65536 int
#define WB_KSORT_Y     4225280   // 65536 int
#define WB_PS0         4487424   // 65536 uint2
#define WB_PS1         5011712   // 65536 uint2

// ---- output float offsets ----
#define OFF_OUT_ZQ   0
#define OFF_OUT_DIS  16777216
#define OFF_OUT_SIDX 16777217
#define OFF_OUT_YIDX 16842753

typedef __attribute__((ext_vector_type(8)))  _Float16 f16x8;
typedef __attribute__((ext_vector_type(4)))  float    f32x4;

__device__ __forceinline__ unsigned int umn(unsigned int a, unsigned int b) { return a < b ? a : b; }
__device__ __forceinline__ unsigned int umx(unsigned int a, unsigned int b) { return a > b ? a : b; }

// ---------------------------------------------------------------------------
// Codebook prep: fp16 fragment image + |e|^2. 384 blocks x 4 waves = 1536 codes.
__global__ void prep_e(const float* __restrict__ Es, const float* __restrict__ Ey,
                       unsigned short* __restrict__ eimg, float* __restrict__ en2) {
    int wave = threadIdx.x >> 6, lane = threadIdx.x & 63;
    int k = blockIdx.x * 4 + wave;       // 0..1535
    const float* E = (k < KS) ? (Es + (size_t)k * CDIM) : (Ey + (size_t)(k - KS) * CDIM);
    float4 v = *(const float4*)(E + lane * 4);
    float nrm = v.x * v.x + v.y * v.y + v.z * v.z + v.w * v.w;
#pragma unroll
    for (int off = 32; off > 0; off >>= 1) nrm += __shfl_down(nrm, off);
    if (lane == 0) en2[k] = nrm;

    unsigned short q0 = __builtin_bit_cast(unsigned short, (_Float16)v.x);
    unsigned short q1 = __builtin_bit_cast(unsigned short, (_Float16)v.y);
    unsigned short q2 = __builtin_bit_cast(unsigned short, (_Float16)v.z);
    unsigned short q3 = __builtin_bit_cast(unsigned short, (_Float16)v.w);
    uint2 hp = make_uint2((unsigned)q0 | ((unsigned)q1 << 16),
                          (unsigned)q2 | ((unsigned)q3 << 16));
    int c0 = lane * 4;
    int kc = c0 >> 5, g = (c0 >> 3) & 3, j0 = c0 & 7;
    size_t byteoff = (size_t)(k >> 4) * 8192 + (size_t)kc * 1024
                   + (size_t)(g * 16 + (k & 15)) * 16 + (size_t)j0 * 2;
    *(uint2*)((char*)eimg + byteoff) = hp;
}

// ---------------------------------------------------------------------------
__device__ __forceinline__ void stage1(const unsigned short* __restrict__ eimg,
                                       int chunk, char* lds, int wave, int lane) {
    const char* gs = (const char*)eimg + (size_t)chunk * 8192 + wave * 2048 + lane * 16;
    char* ls = lds + wave * 2048;
    __builtin_amdgcn_global_load_lds(
        (const __attribute__((address_space(1))) void*)gs,
        (__attribute__((address_space(3))) void*)ls, 16, 0, 0);
    __builtin_amdgcn_global_load_lds(
        (const __attribute__((address_space(1))) void*)(gs + 1024),
        (__attribute__((address_space(3))) void*)(ls + 1024), 16, 0, 0);
}

#define WAITV(n)                                                               \
    asm volatile("s_waitcnt vmcnt(" #n ")");                                   \
    __builtin_amdgcn_sched_barrier(0);

#define PSFLUSH(dst)                                                           \
    {                                                                          \
        _Pragma("unroll")                                                      \
        for (int rg = 0; rg < 2; ++rg)                                         \
        _Pragma("unroll")                                                      \
        for (int q = 0; q < 4; ++q) {                                          \
            unsigned int v1 = m1a[rg][q], v2 = m2a[rg][q];                     \
            _Pragma("unroll")                                                  \
            for (int m = 8; m >= 1; m >>= 1) {                                 \
                unsigned int o1 = (unsigned int)__shfl_xor((int)v1, m);        \
                unsigned int o2 = (unsigned int)__shfl_xor((int)v2, m);        \
                v2 = umn(umn(v2, o2), umx(v1, o1));                            \
                v1 = umn(v1, o1);                                              \
            }                                                                  \
            if ((lane & 15) == 0) {                                            \
                int n = n0 + rg * 16 + (lane >> 4) * 4 + q;                    \
                dst[n] = make_uint2(v1, v2);                                   \
            }                                                                  \
            m1a[rg][q] = 0xFFFFFFFFu; m2a[rg][q] = 0xFFFFFFFFu;                \
        }                                                                      \
    }

#define FLUSHY()                                                               \
    {                                                                          \
        _Pragma("unroll")                                                      \
        for (int rg = 0; rg < 2; ++rg)                                         \
        _Pragma("unroll")                                                      \
        for (int q = 0; q < 4; ++q) {                                          \
            unsigned int v1 = m1a[rg][q], v2 = m2a[rg][q];                     \
            _Pragma("unroll")                                                  \
            for (int m = 8; m >= 1; m >>= 1) {                                 \
                unsigned int o1 = (unsigned int)__shfl_xor((int)v1, m);        \
                unsigned int o2 = (unsigned int)__shfl_xor((int)v2, m);        \
                v2 = umn(umn(v2, o2), umx(v1, o1));                            \
                v1 = umn(v1, o1);                                              \
            }                                                                  \
            if ((lane & 15) == 0) {                                            \
                int kw = (int)(v1 & 0x7FFu) - KS;                              \
                int n = n0 + rg * 16 + (lane >> 4) * 4 + q;                    \
                yidx_f[n] = (float)kw;                                         \
                yidx_i[n] = kw;                                                \
                atomicAdd(&cnt_y[kw], 1);                                      \
                if ((v1 >> 11) + 4 > (v2 >> 11)) {                             \
                    int k2w = (int)(v2 & 0x7FFu) - KS;                         \
                    int pp = atomicAdd(&rescue_cnt[1], 1);                     \
                    if (pp < 65536) rlist_y[pp] = n | (k2w << 16);             \
                }                                                              \
            }                                                                  \
        }                                                                      \
    }

// ---------------------------------------------------------------------------
// Fused phase-1: blocks [0,1024) = MFMA assign (reads z directly);
// blocks [1024,3072) = z -> zf transpose (fills assign's idle slots).
__launch_bounds__(256, 4)
__global__ void main1_kernel(const float* __restrict__ z, const unsigned short* __restrict__ eimg,
                             const float* __restrict__ en2g, float* __restrict__ zf,
                             uint2* __restrict__ ps0, uint2* __restrict__ ps1,
                             float* __restrict__ yidx_f, int* __restrict__ yidx_i,
                             int* __restrict__ cnt_y, int* __restrict__ rescue_cnt,
                             int* __restrict__ rlist_y) {
    __shared__ char lds_raw[38912];

    if (blockIdx.x < 1024) {
        char (*sh)[8192] = (char(*)[8192])lds_raw;
        float* en2l = (float*)(lds_raw + 32768);
        const int tid = threadIdx.x, wave = tid >> 6, lane = tid & 63;
        const int half = blockIdx.x & 1;
        const int n0 = (blockIdx.x >> 1) * 128 + wave * 32;
        const int cb = half * 48;

        for (int i = tid; i < KTOT; i += 256) en2l[i] = en2g[i];

        const int b = n0 >> 12;
        const int sb = (n0 & 4095) + (lane & 15);
        const float* zb = z + (size_t)b * CDIM * SPB;
        const int g8 = (lane >> 4) * 8;
        f16x8 A[2][8];
#pragma unroll
        for (int rg = 0; rg < 2; ++rg) {
#pragma unroll
            for (int kc = 0; kc < 8; ++kc) {
                f16x8 a;
#pragma unroll
                for (int j = 0; j < 8; ++j)
                    a[j] = (_Float16)zb[(size_t)(g8 + kc * 32 + j) * SPB + sb + rg * 16];
                A[rg][kc] = a;
            }
        }

        unsigned int m1a[2][4], m2a[2][4];
#pragma unroll
        for (int rg = 0; rg < 2; ++rg)
#pragma unroll
            for (int q = 0; q < 4; ++q) { m1a[rg][q] = 0xFFFFFFFFu; m2a[rg][q] = 0xFFFFFFFFu; }

        stage1(eimg, cb + 0, &sh[0][0], wave, lane);
        stage1(eimg, cb + 1, &sh[1][0], wave, lane);
        stage1(eimg, cb + 2, &sh[2][0], wave, lane);
        __syncthreads();

#pragma unroll 1
        for (int i = 0; i < 48; ++i) {
            if (i < 46)       { WAITV(4); }
            else if (i == 46) { WAITV(2); }
            else              { WAITV(0); }
            __builtin_amdgcn_s_barrier();
            asm volatile("" ::: "memory");
            if (i + 3 < 48) stage1(eimg, cb + i + 3, &sh[(i + 3) & 3][0], wave, lane);

            const int chunk = cb + i;
            const char* bb = &sh[i & 3][0] + lane * 16;
            f32x4 acc0 = {}, acc1 = {};
#pragma unroll
            for (int kc = 0; kc < 8; ++kc) {
                f16x8 B = *(const f16x8*)(bb + kc * 1024);
                acc0 = __builtin_amdgcn_mfma_f32_16x16x32_f16(A[0][kc], B, acc0, 0, 0, 0);
                acc1 = __builtin_amdgcn_mfma_f32_16x16x32_f16(A[1][kc], B, acc1, 0, 0, 0);
            }
            const int kcode = chunk * 16 + (lane & 15);
            const float en0 = en2l[kcode] + 512.0f;
            const unsigned int tag = (unsigned int)kcode;
#pragma unroll
            for (int q = 0; q < 4; ++q) {
                float d0 = fmaf(-2.f, acc0[q], en0);
                unsigned int du0 = (__float_as_uint(d0) & 0xFFFFF800u) | tag;
                m2a[0][q] = umn(m2a[0][q], umx(m1a[0][q], du0));
                m1a[0][q] = umn(m1a[0][q], du0);
                float d1 = fmaf(-2.f, acc1[q], en0);
                unsigned int du1 = (__float_as_uint(d1) & 0xFFFFF800u) | tag;
                m2a[1][q] = umn(m2a[1][q], umx(m1a[1][q], du1));
                m1a[1][q] = umn(m1a[1][q], du1);
            }

            if (half == 1 && i == 15) PSFLUSH(ps1);
        }

        if (half == 0) { PSFLUSH(ps0); }
        else           { FLUSHY(); }
    } else {
        float (*Zs)[257] = (float(*)[257])lds_raw;
        int blk = blockIdx.x - 1024;
        int n0 = blk * 32, b = n0 >> 12, s0 = n0 & 4095;
        int t = threadIdx.x;
        const float* zb = z + (size_t)b * CDIM * SPB + s0;
#pragma unroll
        for (int i = 0; i < 32; ++i) {
            int l = i * 256 + t;
            int c = l >> 5, s = l & 31;
            Zs[s][c] = zb[(size_t)c * SPB + s];
        }
        __syncthreads();
#pragma unroll
        for (int j = 0; j < 8; ++j) {
            int gid = j * 256 + t;
            int nl = gid >> 6, fg = gid & 63;
            float4 v = *(const float4*)(&Zs[nl][fg * 4]);
            *(float4*)(&zf[(size_t)(n0 + nl) * 256 + fg * 4]) = v;
        }
    }
}

// ---------------------------------------------------------------------------
// Fused merge + rescue: blocks [0,256) merge book-S partials for their 256
// rows, queue near-ties in LDS, then re-rank them exactly (block-local, no
// grid sync). Blocks [256,512) drain the Y rescue list from main1.
__global__ void merge_rescue_kernel(const float* __restrict__ zf,
                                    const float* __restrict__ Es, const float* __restrict__ Ey,
                                    const float* __restrict__ en2,
                                    const uint2* __restrict__ ps0, const uint2* __restrict__ ps1,
                                    float* __restrict__ sidx_f, float* __restrict__ yidx_f,
                                    int* __restrict__ sidx_i, int* __restrict__ yidx_i,
                                    int* __restrict__ cnt_s, int* __restrict__ cnt_y,
                                    const int* __restrict__ rcnt_y, const int* __restrict__ rlist_y) {
    const int t = threadIdx.x, lane = t & 63, wv = t >> 6;
    if (blockIdx.x < 256) {
        __shared__ int qn[256], qk2[256];
        __shared__ int qc;
        if (t == 0) qc = 0;
        __syncthreads();
        int n = blockIdx.x * 256 + t;
        uint2 pa = ps0[n], pb = ps1[n];
        unsigned int v1 = umn(pa.x, pb.x);
        unsigned int v2 = umn(umn(pa.y, pb.y), umx(pa.x, pb.x));
        int kw = (int)(v1 & 0x7FFu);
        sidx_f[n] = (float)kw;
        sidx_i[n] = kw;
        atomicAdd(&cnt_s[kw], 1);
        if ((v1 >> 11) + 4 > (v2 >> 11)) {
            int p = atomicAdd(&qc, 1);
            qn[p] = n;
            qk2[p] = (int)(v2 & 0x7FFu);
        }
        __syncthreads();
        int ce = qc;
        for (int e = wv; e < ce; e += 4) {
            int nn = qn[e], k2 = qk2[e];
            int k1 = sidx_i[nn];
            float4 zv = *(const float4*)(zf + (size_t)nn * 256 + lane * 4);
            float4 ea = *(const float4*)(Es + (size_t)k1 * 256 + lane * 4);
            float4 ec = *(const float4*)(Es + (size_t)k2 * 256 + lane * 4);
            float d1 = zv.x * ea.x + zv.y * ea.y + zv.z * ea.z + zv.w * ea.w;
            float d2 = zv.x * ec.x + zv.y * ec.y + zv.z * ec.z + zv.w * ec.w;
#pragma unroll
            for (int off = 32; off > 0; off >>= 1) {
                d1 += __shfl_down(d1, off);
                d2 += __shfl_down(d2, off);
            }
            if (lane == 0) {
                float dist1 = en2[k1] - 2.f * d1;
                float dist2 = en2[k2] - 2.f * d2;
                int nk = (dist2 < dist1 || (dist2 == dist1 && k2 < k1)) ? k2 : k1;
                if (nk != k1) {
                    atomicSub(&cnt_s[k1], 1);
                    atomicAdd(&cnt_s[nk], 1);
                    sidx_i[nn] = nk;
                    sidx_f[nn] = (float)nk;
                }
            }
        }
    } else {
        int cy = *rcnt_y; if (cy > 65536) cy = 65536;
        const int nw = 256 * 4;
        for (int e = (blockIdx.x - 256) * 4 + wv; e < cy; e += nw) {
            unsigned int ent = (unsigned int)rlist_y[e];
            int nn = (int)(ent & 0xFFFFu);
            int k2 = (int)(ent >> 16);
            int k1 = yidx_i[nn];
            float4 zv = *(const float4*)(zf + (size_t)nn * 256 + lane * 4);
            float4 ea = *(const float4*)(Ey + (size_t)k1 * 256 + lane * 4);
            float4 ec = *(const float4*)(Ey + (size_t)k2 * 256 + lane * 4);
            float d1 = zv.x * ea.x + zv.y * ea.y + zv.z * ea.z + zv.w * ea.w;
            float d2 = zv.x * ec.x + zv.y * ec.y + zv.z * ec.z + zv.w * ec.w;
#pragma unroll
            for (int off = 32; off > 0; off >>= 1) {
                d1 += __shfl_down(d1, off);
                d2 += __shfl_down(d2, off);
            }
            if (lane == 0) {
                float dist1 = en2[KS + k1] - 2.f * d1;
                float dist2 = en2[KS + k2] - 2.f * d2;
                int nk = (dist2 < dist1 || (dist2 == dist1 && k2 < k1)) ? k2 : k1;
                if (nk != k1) {
                    atomicSub(&cnt_y[k1], 1);
                    atomicAdd(&cnt_y[nk], 1);
                    yidx_i[nn] = nk;
                    yidx_f[nn] = (float)nk;
                }
            }
        }
    }
}

// ---------------------------------------------------------------------------
// Per-codebook: prefix-sum of counts (sort bases) + EMA balance scale.
__global__ void scanbal_kernel(const float* __restrict__ cs_in, const float* __restrict__ cy_in,
                               const int* __restrict__ cnt_s, const int* __restrict__ cnt_y,
                               int* __restrict__ cur_s, int* __restrict__ cur_y,
                               float* __restrict__ scale_s, float* __restrict__ scale_y) {
    __shared__ int   sc[1024];
    __shared__ float sf[1024];
    int K = blockIdx.x ? KY : KS;
    const float* csi = blockIdx.x ? cy_in : cs_in;
    const int*   cnt = blockIdx.x ? cnt_y : cnt_s;
    int* cur  = blockIdx.x ? cur_y  : cur_s;
    float* scale = blockIdx.x ? scale_y : scale_s;
    int t = threadIdx.x;
    int c = (t < K) ? cnt[t] : 0;
    float ncs = (t < K) ? (csi[t] * 0.99f + 0.01f * (float)c) : 0.f;
    sc[t] = c;
    __syncthreads();
    for (int off = 1; off < 1024; off <<= 1) {
        int v = sc[t] + ((t >= off) ? sc[t - off] : 0);
        __syncthreads();
        sc[t] = v;
        __syncthreads();
    }
    int incl = sc[t];
    sf[t] = ncs;
    __syncthreads();
    for (int s2 = 512; s2 > 0; s2 >>= 1) {
        if (t < s2) sf[t] += sf[t + s2];
        __syncthreads();
    }
    float nsum = sf[0];
    if (t < K) {
        cur[t]  = incl - c;
        float bal = (ncs + 1e-5f) / (nsum + (float)K * 1e-5f) * nsum;
        scale[t] = 1.0f / bal;
    }
}

__global__ void scatter_kernel(const int* __restrict__ si, const int* __restrict__ yi,
                               int* __restrict__ cur_s, int* __restrict__ cur_y,
                               int* __restrict__ perm_s, int* __restrict__ perm_y,
                               int* __restrict__ ksort_s, int* __restrict__ ksort_y) {
    int i = blockIdx.x * 256 + threadIdx.x;
    if (i < NROWS) {
        int k = si[i]; int p = atomicAdd(&cur_s[k], 1);
        perm_s[p] = i; ksort_s[p] = k;
    } else {
        int n = i - NROWS; int k = yi[n]; int p = atomicAdd(&cur_y[k], 1);
        perm_y[p] = n; ksort_y[p] = k;
    }
}

// ---------------------------------------------------------------------------
// Chunked segmented sum over sorted rows: block = 64 sorted positions.
__global__ void dw_kernel(const float* __restrict__ zf,
                          const int* __restrict__ perm_s, const int* __restrict__ ksort_s,
                          const int* __restrict__ perm_y, const int* __restrict__ ksort_y,
                          float* __restrict__ dw_s, float* __restrict__ dw_y) {
    __shared__ int keys[65];
    __shared__ int rows[64];
    const int t = threadIdx.x;
    int blk = blockIdx.x;
    const int* perm; const int* ks; float* dw; int p0;
    if (blk < NROWS / 64) { perm = perm_s; ks = ksort_s; dw = dw_s; p0 = blk * 64; }
    else                  { perm = perm_y; ks = ksort_y; dw = dw_y; p0 = (blk - NROWS / 64) * 64; }
    if (t < 64) { keys[t] = ks[p0 + t]; rows[t] = perm[p0 + t]; }
    if (t == 64) keys[64] = -1;
    __syncthreads();
    float acc = 0.f;
#pragma unroll 8
    for (int j = 0; j < 64; ++j) {
        acc += zf[(size_t)rows[j] * 256 + t];
        if (keys[j + 1] != keys[j]) {
            atomicAdd(&dw[(size_t)keys[j] * 256 + t], acc);
            acc = 0.f;
        }
    }
}

// ---------------------------------------------------------------------------
// Gather with on-the-fly emb computation (plain atomicAdd for dis; NO
// device-scope fences).
__global__ void gather_kernel(const float* __restrict__ avg_s, const float* __restrict__ avg_y,
                              const float* __restrict__ dw_s, const float* __restrict__ dw_y,
                              const float* __restrict__ scale_s, const float* __restrict__ scale_y,
                              const int* __restrict__ sidx, const int* __restrict__ yidx,
                              float* __restrict__ zq, float* __restrict__ disacc) {
    __shared__ float qb[256 * 17];
    __shared__ int   si[16], yi[16];
    __shared__ float scs[16], scy[16];
    __shared__ float red[256];
    const int g  = blockIdx.x;        // b*256 + hw
    const int b  = g >> 8;
    const int hw = g & 255;
    const int t  = threadIdx.x;       // channel
    if (t < 16) {
        int n = b * SPB + hw * 16 + t;
        int k = sidx[n];
        si[t] = k;
        scs[t] = scale_s[k];
    } else if (t < 32) {
        int n = b * SPB + hw * 16 + (t - 16);
        int k = yidx[n];
        yi[t - 16] = k;
        scy[t - 16] = scale_y[k];
    }
    __syncthreads();
    float ns = 0.f, ny = 0.f, dot = 0.f;
#pragma unroll
    for (int d = 0; d < 16; ++d) {
        size_t so = (size_t)si[d] * CDIM + t;
        size_t yo = (size_t)yi[d] * CDIM + t;
        float s = fmaf(0.01f, dw_s[so], avg_s[so] * 0.99f) * scs[d];
        float y = fmaf(0.01f, dw_y[yo], avg_y[yo] * 0.99f) * scy[d];
        ns  = fmaf(s, s, ns);
        ny  = fmaf(y, y, ny);
        dot = fmaf(s, y, dot);
        qb[t * 17 + d] = 0.5f * (s + y);
    }
    float den = fmaxf(sqrtf(ns), 1e-12f) * fmaxf(sqrtf(ny), 1e-12f);
    float val = dot / den;
    red[t] = val * val;
    __syncthreads();
    for (int s = 128; s > 0; s >>= 1) {
        if (t < s) red[t] += red[t + s];
        __syncthreads();
    }
    if (t == 0) atomicAdd(disacc, red[0]);
    float* zg = zq + (size_t)b * CDIM * SPB + hw * 16;
#pragma unroll
    for (int j = 0; j < 16; ++j) {
        int e = j * 256 + t;
        int c = e >> 4, d = e & 15;
        zg[(size_t)c * SPB + d] = qb[c * 17 + d];
    }
}

__global__ void fin_kernel(const float* __restrict__ disacc, float* __restrict__ out_dis) {
    *out_dis = *disacc * (1.0f / 1048576.0f);
}

// ---------------------------------------------------------------------------
extern "C" void kernel_launch(void* const* d_in, const int* in_sizes, int n_in,
                              void* d_out, int out_size, void* d_ws, size_t ws_size,
                              hipStream_t stream) {
    const float* z     = (const float*)d_in[0];
    const float* Es    = (const float*)d_in[1];
    const float* Ey    = (const float*)d_in[2];
    const float* s_cs  = (const float*)d_in[3];
    const float* y_cs  = (const float*)d_in[4];
    const float* s_avg = (const float*)d_in[5];
    const float* y_avg = (const float*)d_in[6];
    float* out = (float*)d_out;
    char*  w   = (char*)d_ws;

    unsigned short* eimg = (unsigned short*)(w + WB_EIMG);
    float* en2    = (float*)(w + WB_EN2);
    int* idxs_i   = (int*)(w + WB_IDXS_I);
    int* idxy_i   = (int*)(w + WB_IDXY_I);
    int* cnt_s    = (int*)(w + WB_CNT_S);
    int* cnt_y    = (int*)(w + WB_CNT_Y);
    int* r_cnt    = (int*)(w + WB_RESCUE_CNT);
    int* rlist_y  = (int*)(w + WB_RLIST_Y);
    int* cur_s    = (int*)(w + WB_CUR_S);
    int* cur_y    = (int*)(w + WB_CUR_Y);
    float* scale_s = (float*)(w + WB_SCALE_S);
    float* scale_y = (float*)(w + WB_SCALE_Y);
    int* perm_s   = (int*)(w + WB_PERM_S);
    int* perm_y   = (int*)(w + WB_PERM_Y);
    int* ksort_s  = (int*)(w + WB_KSORT_S);
    int* ksort_y  = (int*)(w + WB_KSORT_Y);
    float* dw_s   = (float*)(w + WB_DW_S);
    float* dw_y   = (float*)(w + WB_DW_Y);
    uint2* ps0    = (uint2*)(w + WB_PS0);
    uint2* ps1    = (uint2*)(w + WB_PS1);

    float* zf     = out + OFF_OUT_ZQ;        // zq region reused as fp32 z^T scratch
    float* sidx_f = out + OFF_OUT_SIDX;
    float* yidx_f = out + OFF_OUT_YIDX;

    hipMemsetAsync(w, 0, WB_ZERO_BYTES, stream);

    prep_e<<<384, 256, 0, stream>>>(Es, Ey, eimg, en2);

    main1_kernel<<<1024 + 2048, 256, 0, stream>>>(
        z, eimg, en2, zf, ps0, ps1, yidx_f, idxy_i, cnt_y, r_cnt, rlist_y);

    merge_rescue_kernel<<<512, 256, 0, stream>>>(zf, Es, Ey, en2, ps0, ps1,
                                                 sidx_f, yidx_f, idxs_i, idxy_i,
                                                 cnt_s, cnt_y, r_cnt + 1, rlist_y);

    scanbal_kernel<<<2, 1024, 0, stream>>>(s_cs, y_cs, cnt_s, cnt_y,
                                           cur_s, cur_y, scale_s, scale_y);
    scatter_kernel<<<2 * NROWS / 256, 256, 0, stream>>>(idxs_i, idxy_i, cur_s, cur_y,
                                                        perm_s, perm_y, ksort_s, ksort_y);
    dw_kernel<<<2 * NROWS / 64, 256, 0, stream>>>(zf, perm_s, ksort_s, perm_y, ksort_y, dw_s, dw_y);
    gather_kernel<<<4096, 256, 0, stream>>>(s_avg, y_avg, dw_s, dw_y, scale_s, scale_y,
                                            idxs_i, idxy_i,
                                            out + OFF_OUT_ZQ, (float*)(w + WB_DISACC));
    fin_kernel<<<1, 1, 0, stream>>>((float*)(w + WB_DISACC), out + OFF_OUT_DIS);
}